// Round 6
// baseline (178.390 us; speedup 1.0000x reference)
//
#include <hip/hip_runtime.h>
#include <math.h>

#define Bn 16
#define Nn 256
#define Mm (Nn*(Nn-1)/2)   /* 32640 */
#define CHUNK 4080         /* Mm / 8 */

typedef __attribute__((ext_vector_type(8))) short bf16x8;
typedef __attribute__((ext_vector_type(4))) short short4v;
typedef __attribute__((ext_vector_type(4))) float f32x4;

typedef union { bf16x8 v; short s[8]; __bf16 h[8]; } F8;
typedef union { short4v v; __bf16 h[4]; } F4;

#define MFMA(acc, a, b) \
  acc = __builtin_amdgcn_mfma_f32_16x16x32_bf16((a), (b), (acc), 0, 0, 0)

__device__ __forceinline__ void top2_update(float v, int m,
    float& v1, int& i1, float& v2, int& i2)
{
  bool c1 = (v > v1) || (v == v1 && m < i1);
  bool c2 = (v > v2) || (v == v2 && m < i2);
  float nv2 = c1 ? v1 : (c2 ? v : v2);
  int   ni2 = c1 ? i1 : (c2 ? m : i2);
  v1 = c1 ? v : v1;  i1 = c1 ? m : i1;
  v2 = nv2;          i2 = ni2;
}

// ---------------------------------------------------------------------------
// Prep: W1 (256k x 64h f32) -> wtg bf16 [h][k] (64 x 256), RNE cast.
// ---------------------------------------------------------------------------
__global__ __launch_bounds__(256) void prep_w1t(
    const float* __restrict__ W1, unsigned short* __restrict__ wtg)
{
  const int h = blockIdx.x;      // 0..63
  const int k = threadIdx.x;     // 0..255
  __bf16 b = (__bf16)W1[k * 64 + h];
  wtg[h * 256 + k] = *(unsigned short*)&b;
}

// ---------------------------------------------------------------------------
// Pair kernel: one block = (batch, 16x32 pair tile), 256 thr (4 waves).
// Swapped-operand MFMA: A = W1^T fragments (h x k, from global wtg),
// B = feature fragments (k x pair). Output C[h][pair].
// Steady-state inner loop has NO LDS on the critical path: ojv/cin/bfr all
// hoisted to registers; per (ii,jh): feature build (VALU) + 16 MFMA + epi.
// ---------------------------------------------------------------------------
__global__ __launch_bounds__(256, 4) void pair_kernel(
    const float* __restrict__ O,
    const float* __restrict__ b1,
    const float* __restrict__ W2,
    const float* __restrict__ b2,
    const unsigned short* __restrict__ wtg,
    float* __restrict__ Q,
    float* __restrict__ cand)
{
  __shared__ __align__(16) unsigned short s_oi[16][72]; // bf16, 144B rows
  __shared__ __align__(16) unsigned short s_oj[32][72];
  __shared__ float s_A[16][68];   // A[i][h] (+b1), 272B rows
  __shared__ float s_C[32][68];   // C[j][h]
  __shared__ float s_q[16][36];
  __shared__ float s_w2[64];
  __shared__ float s_red[4][4];

  const int t  = threadIdx.x;
  const int l  = t & 63, wv = t >> 6;
  const int lo = l & 15, g = l >> 4;

  const int blk   = blockIdx.x;
  const int batch = blk / 72;
  int tl          = blk % 72;
  int a = 0;
  while (tl >= 8 - (a >> 1)) { tl -= 8 - (a >> 1); ++a; }
  const int c   = (a >> 1) + tl;
  const int ti0 = a * 16, tj0 = c * 32;

  const float* Ob = O + (size_t)batch * Nn * 64;

  // ---- stage O tiles as bf16 ----
  {
    const float4* Oi4 = (const float4*)(Ob + ti0 * 64);
    {
      int r = t >> 4, c4 = (t & 15) * 4;
      float4 x = Oi4[t];
      F4 p; p.h[0] = (__bf16)x.x; p.h[1] = (__bf16)x.y;
            p.h[2] = (__bf16)x.z; p.h[3] = (__bf16)x.w;
      *(short4v*)&s_oi[r][c4] = p.v;
    }
    const float4* Oj4 = (const float4*)(Ob + tj0 * 64);
    #pragma unroll
    for (int p2 = 0; p2 < 2; ++p2) {
      int v = t + p2 * 256;
      int r = v >> 4, c4 = (v & 15) * 4;
      float4 x = Oj4[v];
      F4 p; p.h[0] = (__bf16)x.x; p.h[1] = (__bf16)x.y;
            p.h[2] = (__bf16)x.z; p.h[3] = (__bf16)x.w;
      *(short4v*)&s_oj[r][c4] = p.v;
    }
    if (t < 64) s_w2[t] = W2[t];
  }
  __syncthreads();

  // ---- Phase 1: A[i][h] = Oi@W1a + b1 ; C[j][h] = Oj@W1b ----
  if (wv < 2) {
    #pragma unroll
    for (int nn = 0; nn < 2; ++nn) {
      const int nf = wv * 2 + nn;
      f32x4 ac = {0.f, 0.f, 0.f, 0.f};
      #pragma unroll
      for (int ks = 0; ks < 2; ++ks) {
        F8 aop; aop.v = *(const bf16x8*)&s_oi[lo][ks * 32 + g * 8];
        F8 bop; bop.v = *(const bf16x8*)&wtg[(nf * 16 + lo) * 256 + ks * 32 + g * 8];
        MFMA(ac, aop.v, bop.v);
      }
      const float bb = b1[nf * 16 + lo];
      #pragma unroll
      for (int r = 0; r < 4; ++r)
        s_A[g * 4 + r][nf * 16 + lo] = ac[r] + bb;
    }
  } else {
    const int mf = wv - 2;
    #pragma unroll
    for (int nf = 0; nf < 4; ++nf) {
      f32x4 ac = {0.f, 0.f, 0.f, 0.f};
      #pragma unroll
      for (int ks = 0; ks < 2; ++ks) {
        F8 aop; aop.v = *(const bf16x8*)&s_oj[mf * 16 + lo][ks * 32 + g * 8];
        F8 bop; bop.v = *(const bf16x8*)&wtg[(nf * 16 + lo) * 256 + 64 + ks * 32 + g * 8];
        MFMA(ac, aop.v, bop.v);
      }
      #pragma unroll
      for (int r = 0; r < 4; ++r)
        s_C[mf * 16 + g * 4 + r][nf * 16 + lo] = ac[r];
    }
  }

  // ---- hoist pairwise W fragments (iteration-invariant, from global) ----
  F8 bfr[4][4];   // [ks][nf], k = 128 + ks*32 + g*8, h-row = nf*16+lo
  #pragma unroll
  for (int ks = 0; ks < 4; ++ks)
    #pragma unroll
    for (int nf = 0; nf < 4; ++nf)
      bfr[ks][nf].v = *(const bf16x8*)&wtg[(nf * 16 + lo) * 256 + 128 + ks * 32 + g * 8];

  __syncthreads();

  // ---- hoist j-side values and C-init (invariant across ii) ----
  float ojv[2][16];
  #pragma unroll
  for (int jh = 0; jh < 2; ++jh) {
    F8 u0, u1;
    u0.v = *(const bf16x8*)&s_oj[jh * 16 + lo][g * 8];
    u1.v = *(const bf16x8*)&s_oj[jh * 16 + lo][32 + g * 8];
    #pragma unroll
    for (int e = 0; e < 8; ++e) {
      ojv[jh][e]     = (float)u0.h[e];
      ojv[jh][8 + e] = (float)u1.h[e];
    }
  }
  f32x4 cin[2][4];
  #pragma unroll
  for (int jh = 0; jh < 2; ++jh)
    #pragma unroll
    for (int nf = 0; nf < 4; ++nf)
      cin[jh][nf] = *(const f32x4*)&s_C[jh * 16 + lo][nf * 16 + g * 4];

  // ---- main loop: wave owns i-rows wv*4 .. wv*4+3 ----
  #pragma unroll
  for (int ii = 0; ii < 4; ++ii) {
    const int iL = wv * 4 + ii;

    f32x4 as4[4];
    #pragma unroll
    for (int nf = 0; nf < 4; ++nf)
      as4[nf] = *(const f32x4*)&s_A[iL][nf * 16 + g * 4];

    float oiv[16];
    {
      F8 u0, u1;
      u0.v = *(const bf16x8*)&s_oi[iL][g * 8];
      u1.v = *(const bf16x8*)&s_oi[iL][32 + g * 8];
      #pragma unroll
      for (int e = 0; e < 8; ++e) {
        oiv[e]     = (float)u0.h[e];
        oiv[8 + e] = (float)u1.h[e];
      }
    }

    #pragma unroll
    for (int jh = 0; jh < 2; ++jh) {
      // features for pair col lo: j = tj0 + jh*16 + lo
      F8 fb0, fb1, fb2, fb3;
      #pragma unroll
      for (int e = 0; e < 8; ++e) {
        float p0 = ojv[jh][e], p1 = ojv[jh][8 + e];
        float d0 = oiv[e] - p0,    d1 = oiv[8 + e] - p1;
        fb0.h[e] = (__bf16)fabsf(d0);
        fb1.h[e] = (__bf16)fabsf(d1);
        fb2.h[e] = (__bf16)(oiv[e] * p0);
        fb3.h[e] = (__bf16)(oiv[8 + e] * p1);
      }

      f32x4 acc0 = as4[0] + cin[jh][0];
      f32x4 acc1 = as4[1] + cin[jh][1];
      f32x4 acc2 = as4[2] + cin[jh][2];
      f32x4 acc3 = as4[3] + cin[jh][3];

      MFMA(acc0, bfr[0][0].v, fb0.v); MFMA(acc1, bfr[0][1].v, fb0.v);
      MFMA(acc2, bfr[0][2].v, fb0.v); MFMA(acc3, bfr[0][3].v, fb0.v);
      MFMA(acc0, bfr[1][0].v, fb1.v); MFMA(acc1, bfr[1][1].v, fb1.v);
      MFMA(acc2, bfr[1][2].v, fb1.v); MFMA(acc3, bfr[1][3].v, fb1.v);
      MFMA(acc0, bfr[2][0].v, fb2.v); MFMA(acc1, bfr[2][1].v, fb2.v);
      MFMA(acc2, bfr[2][2].v, fb2.v); MFMA(acc3, bfr[2][3].v, fb2.v);
      MFMA(acc0, bfr[3][0].v, fb3.v); MFMA(acc1, bfr[3][1].v, fb3.v);
      MFMA(acc2, bfr[3][2].v, fb3.v); MFMA(acc3, bfr[3][3].v, fb3.v);

      // epilogue: relu + W2 partial, reduce over g (2 shfl)
      float part = 0.f;
      {
        f32x4 w0 = *(const f32x4*)&s_w2[0 * 16 + g * 4];
        f32x4 w1 = *(const f32x4*)&s_w2[1 * 16 + g * 4];
        f32x4 w2q = *(const f32x4*)&s_w2[2 * 16 + g * 4];
        f32x4 w3 = *(const f32x4*)&s_w2[3 * 16 + g * 4];
        #pragma unroll
        for (int r = 0; r < 4; ++r) {
          part = fmaf(fmaxf(acc0[r], 0.f), w0[r], part);
          part = fmaf(fmaxf(acc1[r], 0.f), w1[r], part);
          part = fmaf(fmaxf(acc2[r], 0.f), w2q[r], part);
          part = fmaf(fmaxf(acc3[r], 0.f), w3[r], part);
        }
      }
      part += __shfl_xor(part, 16);
      part += __shfl_xor(part, 32);
      if (g == 0) s_q[iL][jh * 16 + lo] = part;
    }
  }
  __syncthreads();

  // ---- final: Q store + block top-2 candidates ----
  {
    const float b2v = b2[0];
    const int e0 = t * 2;
    const int row = e0 >> 5, col0 = e0 & 31;
    const int i = ti0 + row;
    float v1 = -INFINITY, v2 = -INFINITY;
    int   i1 = 0x7fffffff, i2 = 0x7fffffff;
    const int mbase = i * (Nn - 1) - (i * (i - 1)) / 2 - i - 1;
    #pragma unroll
    for (int e = 0; e < 2; ++e) {
      const int col = col0 + e;
      const int j = tj0 + col;
      const float qv = s_q[row][col] + b2v;
      if (j > i) {
        const int m = mbase + j;
        Q[(size_t)batch * Mm + m] = qv;
        top2_update(qv, m, v1, i1, v2, i2);
      }
    }
    #pragma unroll
    for (int s = 1; s < 64; s <<= 1) {
      float u1 = __shfl_xor(v1, s); int j1 = __shfl_xor(i1, s);
      float u2 = __shfl_xor(v2, s); int j2 = __shfl_xor(i2, s);
      top2_update(u1, j1, v1, i1, v2, i2);
      top2_update(u2, j2, v1, i1, v2, i2);
    }
    if (l == 0) {
      s_red[wv][0] = v1; s_red[wv][1] = __int_as_float(i1);
      s_red[wv][2] = v2; s_red[wv][3] = __int_as_float(i2);
    }
    __syncthreads();
    if (t == 0) {
      float a1 = s_red[0][0]; int x1 = __float_as_int(s_red[0][1]);
      float a2 = s_red[0][2]; int x2 = __float_as_int(s_red[0][3]);
      #pragma unroll
      for (int e = 1; e < 4; ++e) {
        top2_update(s_red[e][0], __float_as_int(s_red[e][1]), a1, x1, a2, x2);
        top2_update(s_red[e][2], __float_as_int(s_red[e][3]), a1, x1, a2, x2);
      }
      float* cp = cand + (size_t)blk * 4;
      cp[0] = a1; cp[1] = __int_as_float(x1);
      cp[2] = a2; cp[3] = __int_as_float(x2);
    }
  }
}

// ---------------------------------------------------------------------------
// Rank+mask kernel: grid (B x 8). Each block redundantly merges the 144
// candidates -> top-8 (by bf16 Q), recomputes those 8 exactly in fp32,
// picks exact top-2 (jax tie rule: lower index), writes its mask slice.
// ---------------------------------------------------------------------------
__global__ __launch_bounds__(256) void rankmask_kernel(
    const float* __restrict__ O, const float* __restrict__ W1,
    const float* __restrict__ b1, const float* __restrict__ W2,
    const float* __restrict__ cand, float* __restrict__ mask)
{
  const int b   = blockIdx.x >> 3;
  const int cch = blockIdx.x & 7;
  const int t   = threadIdx.x;
  __shared__ float s_cv[144];
  __shared__ int   s_ci[144];
  __shared__ int   s_m[8];
  __shared__ int   s_ij[8][2];
  __shared__ float s_or[8][2][64];
  __shared__ float s_part[8][32];
  __shared__ int   s_k0, s_k1;

  if (t < 144) {
    const float* cp = cand + (size_t)(b * 72 + (t >> 1)) * 4;
    s_cv[t] = cp[(t & 1) * 2];
    s_ci[t] = __float_as_int(cp[(t & 1) * 2 + 1]);
  }
  __syncthreads();
  if (t < 144) {
    float v = s_cv[t]; int m = s_ci[t];
    int rank = 0;
    for (int e = 0; e < 144; ++e) {
      float u = s_cv[e]; int n = s_ci[e];
      rank += (u > v || (u == v && n < m)) ? 1 : 0;
    }
    if (rank < 8) s_m[rank] = m;
  }
  __syncthreads();
  if (t < 16) {
    int m = s_m[t >> 1];
    int i = 0, rem = m;
    while (rem >= Nn - 1 - i) { rem -= Nn - 1 - i; ++i; }
    int j = i + 1 + rem;
    s_ij[t >> 1][t & 1] = (t & 1) ? j : i;
  }
  __syncthreads();
  {
    int cc = t >> 5, rr = (t >> 4) & 1, c4 = (t & 15) * 4;
    int row = s_ij[cc][rr];
    *(float4*)&s_or[cc][rr][c4] = *(const float4*)&O[((size_t)b * Nn + row) * 64 + c4];
  }
  __syncthreads();
  {
    int cc = t >> 5, hh = t & 31, h2 = hh * 2;
    float z0 = b1[h2], z1 = b1[h2 + 1];
    #pragma unroll 8
    for (int d = 0; d < 64; ++d) {
      float oi = s_or[cc][0][d], oj = s_or[cc][1][d];
      float f3 = fabsf(oi - oj), f4 = oi * oj;
      float2 wa = *(const float2*)&W1[(d      ) * 64 + h2];
      float2 wb = *(const float2*)&W1[(64 + d ) * 64 + h2];
      float2 wc = *(const float2*)&W1[(128 + d) * 64 + h2];
      float2 wd = *(const float2*)&W1[(192 + d) * 64 + h2];
      z0 += oi * wa.x + oj * wb.x + f3 * wc.x + f4 * wd.x;
      z1 += oi * wa.y + oj * wb.y + f3 * wc.y + f4 * wd.y;
    }
    s_part[cc][hh] = fmaxf(z0, 0.f) * W2[h2] + fmaxf(z1, 0.f) * W2[h2 + 1];
  }
  __syncthreads();
  if (t == 0) {
    float v1 = -INFINITY, v2 = -INFINITY;
    int   i1 = 0x7fffffff, i2 = 0x7fffffff;
    for (int e = 0; e < 8; ++e) {
      float s = 0.f;
      for (int u = 0; u < 32; ++u) s += s_part[e][u];
      top2_update(s, s_m[e], v1, i1, v2, i2);
    }
    s_k0 = i1; s_k1 = i2;
  }
  __syncthreads();

  const int k0 = s_k0, k1 = s_k1;
  float* mb = mask + (size_t)b * Mm;
  const int m0 = cch * CHUNK;
  for (int m = m0 + t; m < m0 + CHUNK; m += 256)
    mb[m] = (m == k0 || m == k1) ? 1.0f : 0.0f;
}

extern "C" void kernel_launch(void* const* d_in, const int* in_sizes, int n_in,
                              void* d_out, int out_size, void* d_ws, size_t ws_size,
                              hipStream_t stream) {
  const float* O  = (const float*)d_in[0];
  const float* W1 = (const float*)d_in[1];
  const float* b1 = (const float*)d_in[2];
  const float* W2 = (const float*)d_in[3];
  const float* b2 = (const float*)d_in[4];

  float* Q    = (float*)d_out;
  float* mask = Q + (size_t)Bn * Mm;

  unsigned short* wtg = (unsigned short*)d_ws;                    // 32768 B
  float* cand = (float*)((char*)d_ws + 32768);                    // 18432 B

  prep_w1t<<<dim3(64), dim3(256), 0, stream>>>(W1, wtg);
  pair_kernel<<<dim3(Bn * 72), dim3(256), 0, stream>>>(O, b1, W2, b2, wtg, Q, cand);
  rankmask_kernel<<<dim3(Bn * 8), dim3(256), 0, stream>>>(O, W1, b1, W2, cand, mask);
}

// Round 7
// 97.654 us; speedup vs baseline: 1.8268x; 1.8268x over previous
//
#include <hip/hip_runtime.h>
#include <math.h>

#define Bn 16
#define Nn 256
#define Mm (Nn*(Nn-1)/2)   /* 32640 */
#define CHUNK 4080         /* Mm / 8 */

typedef __attribute__((ext_vector_type(8))) short bf16x8;
typedef __attribute__((ext_vector_type(4))) short short4v;
typedef __attribute__((ext_vector_type(4))) float f32x4;

typedef union { bf16x8 v; short s[8]; __bf16 h[8]; } F8;
typedef union { short4v v; __bf16 h[4]; } F4;

#define MFMA(acc, a, b) \
  acc = __builtin_amdgcn_mfma_f32_16x16x32_bf16((a), (b), (acc), 0, 0, 0)

__device__ __forceinline__ void top2_update(float v, int m,
    float& v1, int& i1, float& v2, int& i2)
{
  bool c1 = (v > v1) || (v == v1 && m < i1);
  bool c2 = (v > v2) || (v == v2 && m < i2);
  float nv2 = c1 ? v1 : (c2 ? v : v2);
  int   ni2 = c1 ? i1 : (c2 ? m : i2);
  v1 = c1 ? v : v1;  i1 = c1 ? m : i1;
  v2 = nv2;          i2 = ni2;
}

// ---------------------------------------------------------------------------
// Prep: W1 (256k x 64h f32) -> wtg bf16 [h][k] (64 x 256), RNE cast.
// ---------------------------------------------------------------------------
__global__ __launch_bounds__(256) void prep_w1t(
    const float* __restrict__ W1, unsigned short* __restrict__ wtg)
{
  const int h = blockIdx.x;      // 0..63
  const int k = threadIdx.x;     // 0..255
  __bf16 b = (__bf16)W1[k * 64 + h];
  wtg[h * 256 + k] = *(unsigned short*)&b;
}

// ---------------------------------------------------------------------------
// Pair kernel: one block = (batch, 16x32 pair tile), 256 thr (4 waves).
// A-operand = W1^T fragments (hoisted, AGPR-eligible), B = feature frags
// built in-register from bf16 oi (read per ii) and bf16 ojb (hoisted).
// acc starts at 0; per-row terms A[i,h]/C[j,h] are added in the epilogue
// (inside the MFMA shadow). No conflicted LDS reads on the loop head.
// Register budget engineered for 3 waves/SIMD: bfr 64 + ojb 16 + transients.
// ---------------------------------------------------------------------------
__global__ __launch_bounds__(256, 3) void pair_kernel(
    const float* __restrict__ O,
    const float* __restrict__ b1,
    const float* __restrict__ W2,
    const float* __restrict__ b2,
    const unsigned short* __restrict__ wtg,
    float* __restrict__ Q,
    float* __restrict__ cand)
{
  __shared__ __align__(16) unsigned short s_oi[16][72]; // bf16, 144B rows
  __shared__ __align__(16) unsigned short s_oj[32][72];
  __shared__ float s_A [16][68];  // A[i][h] (+b1), broadcast b128 reads
  __shared__ float s_CT[64][33];  // C^T[h][j], stride 33 -> 2-way max
  __shared__ float s_q [16][36];
  __shared__ float s_w2[64];
  __shared__ float s_red[4][4];

  const int t  = threadIdx.x;
  const int l  = t & 63, wv = t >> 6;
  const int lo = l & 15, g = l >> 4;

  const int blk   = blockIdx.x;
  const int batch = blk / 72;
  int tl          = blk % 72;
  int a = 0;
  while (tl >= 8 - (a >> 1)) { tl -= 8 - (a >> 1); ++a; }
  const int c   = (a >> 1) + tl;
  const int ti0 = a * 16, tj0 = c * 32;

  const float* Ob = O + (size_t)batch * Nn * 64;

  // ---- hoist pairwise W fragments (global, L2-hot; AGPR-eligible) ----
  F8 bfr[4][4];   // [ks][nf], k = 128 + ks*32 + g*8, h-row = nf*16+lo
  #pragma unroll
  for (int ks = 0; ks < 4; ++ks)
    #pragma unroll
    for (int nf = 0; nf < 4; ++nf)
      bfr[ks][nf].v = *(const bf16x8*)&wtg[(nf * 16 + lo) * 256 + 128 + ks * 32 + g * 8];

  // ---- stage O tiles as bf16 ----
  {
    const float4* Oi4 = (const float4*)(Ob + ti0 * 64);
    {
      int r = t >> 4, c4 = (t & 15) * 4;
      float4 x = Oi4[t];
      F4 p; p.h[0] = (__bf16)x.x; p.h[1] = (__bf16)x.y;
            p.h[2] = (__bf16)x.z; p.h[3] = (__bf16)x.w;
      *(short4v*)&s_oi[r][c4] = p.v;
    }
    const float4* Oj4 = (const float4*)(Ob + tj0 * 64);
    #pragma unroll
    for (int p2 = 0; p2 < 2; ++p2) {
      int v = t + p2 * 256;
      int r = v >> 4, c4 = (v & 15) * 4;
      float4 x = Oj4[v];
      F4 p; p.h[0] = (__bf16)x.x; p.h[1] = (__bf16)x.y;
            p.h[2] = (__bf16)x.z; p.h[3] = (__bf16)x.w;
      *(short4v*)&s_oj[r][c4] = p.v;
    }
    if (t < 64) s_w2[t] = W2[t];
  }
  __syncthreads();

  // ---- Phase 1: A[i][h] = Oi@W1a + b1 ; C^T[h][j] = (Oj@W1b)^T ----
  if (wv < 2) {
    #pragma unroll
    for (int nn = 0; nn < 2; ++nn) {
      const int nf = wv * 2 + nn;
      f32x4 ac = {0.f, 0.f, 0.f, 0.f};
      #pragma unroll
      for (int ks = 0; ks < 2; ++ks) {
        F8 aop; aop.v = *(const bf16x8*)&s_oi[lo][ks * 32 + g * 8];
        F8 bop; bop.v = *(const bf16x8*)&wtg[(nf * 16 + lo) * 256 + ks * 32 + g * 8];
        MFMA(ac, aop.v, bop.v);
      }
      const float bb = b1[nf * 16 + lo];
      #pragma unroll
      for (int r = 0; r < 4; ++r)
        s_A[g * 4 + r][nf * 16 + lo] = ac[r] + bb;
    }
  } else {
    const int mf = wv - 2;
    #pragma unroll
    for (int nf = 0; nf < 4; ++nf) {
      f32x4 ac = {0.f, 0.f, 0.f, 0.f};
      #pragma unroll
      for (int ks = 0; ks < 2; ++ks) {
        F8 aop; aop.v = *(const bf16x8*)&s_oj[mf * 16 + lo][ks * 32 + g * 8];
        F8 bop; bop.v = *(const bf16x8*)&wtg[(nf * 16 + lo) * 256 + 64 + ks * 32 + g * 8];
        MFMA(ac, aop.v, bop.v);
      }
      #pragma unroll
      for (int r = 0; r < 4; ++r)
        s_CT[nf * 16 + lo][mf * 16 + g * 4 + r] = ac[r];   // transposed store
    }
  }
  __syncthreads();

  // ---- hoist j-side values as bf16 (8 VGPR per jh) ----
  F8 ojb[2][2];
  #pragma unroll
  for (int jh = 0; jh < 2; ++jh) {
    ojb[jh][0].v = *(const bf16x8*)&s_oj[jh * 16 + lo][g * 8];
    ojb[jh][1].v = *(const bf16x8*)&s_oj[jh * 16 + lo][32 + g * 8];
  }

  // ---- main loop: wave owns i-rows wv*4 .. wv*4+3 ----
  for (int ii = 0; ii < 4; ++ii) {
    const int iL = wv * 4 + ii;

    // oi row (wave-uniform row, broadcast reads) -> f32
    float oiv[16];
    {
      F8 u0, u1;
      u0.v = *(const bf16x8*)&s_oi[iL][g * 8];
      u1.v = *(const bf16x8*)&s_oi[iL][32 + g * 8];
      #pragma unroll
      for (int e = 0; e < 8; ++e) {
        oiv[e]     = (float)u0.h[e];
        oiv[8 + e] = (float)u1.h[e];
      }
    }
    // A-row terms (broadcast b128), used only in epilogue
    f32x4 as4[4];
    #pragma unroll
    for (int nf = 0; nf < 4; ++nf)
      as4[nf] = *(const f32x4*)&s_A[iL][nf * 16 + g * 4];

    #pragma unroll
    for (int jh = 0; jh < 2; ++jh) {
      // features for pair col lo: j = tj0 + jh*16 + lo
      F8 fb0, fb1, fb2, fb3;
      #pragma unroll
      for (int e = 0; e < 8; ++e) {
        float p0 = (float)ojb[jh][0].h[e];
        float p1 = (float)ojb[jh][1].h[e];
        fb0.h[e] = (__bf16)fabsf(oiv[e]     - p0);
        fb1.h[e] = (__bf16)fabsf(oiv[8 + e] - p1);
        fb2.h[e] = (__bf16)(oiv[e]     * p0);
        fb3.h[e] = (__bf16)(oiv[8 + e] * p1);
      }

      f32x4 acc[4] = {{0.f,0.f,0.f,0.f},{0.f,0.f,0.f,0.f},
                      {0.f,0.f,0.f,0.f},{0.f,0.f,0.f,0.f}};
      #pragma unroll
      for (int nf = 0; nf < 4; ++nf) {
        MFMA(acc[nf], bfr[0][nf].v, fb0.v);
        MFMA(acc[nf], bfr[1][nf].v, fb1.v);
        MFMA(acc[nf], bfr[2][nf].v, fb2.v);
        MFMA(acc[nf], bfr[3][nf].v, fb3.v);
      }

      // epilogue (in MFMA shadow): add A+C terms, relu, W2 dot, 2 shfl
      float part = 0.f;
      #pragma unroll
      for (int nf = 0; nf < 4; ++nf) {
        #pragma unroll
        for (int r = 0; r < 4; ++r) {
          float z = acc[nf][r] + as4[nf][r]
                  + s_CT[nf * 16 + g * 4 + r][jh * 16 + lo];
          part = fmaf(fmaxf(z, 0.f), s_w2[nf * 16 + g * 4 + r], part);
        }
      }
      part += __shfl_xor(part, 16);
      part += __shfl_xor(part, 32);
      if (g == 0) s_q[iL][jh * 16 + lo] = part;
    }
  }
  __syncthreads();

  // ---- final: Q store + block top-2 candidates ----
  {
    const float b2v = b2[0];
    const int e0 = t * 2;
    const int row = e0 >> 5, col0 = e0 & 31;
    const int i = ti0 + row;
    float v1 = -INFINITY, v2 = -INFINITY;
    int   i1 = 0x7fffffff, i2 = 0x7fffffff;
    const int mbase = i * (Nn - 1) - (i * (i - 1)) / 2 - i - 1;
    #pragma unroll
    for (int e = 0; e < 2; ++e) {
      const int col = col0 + e;
      const int j = tj0 + col;
      const float qv = s_q[row][col] + b2v;
      if (j > i) {
        const int m = mbase + j;
        Q[(size_t)batch * Mm + m] = qv;
        top2_update(qv, m, v1, i1, v2, i2);
      }
    }
    #pragma unroll
    for (int s = 1; s < 64; s <<= 1) {
      float u1 = __shfl_xor(v1, s); int j1 = __shfl_xor(i1, s);
      float u2 = __shfl_xor(v2, s); int j2 = __shfl_xor(i2, s);
      top2_update(u1, j1, v1, i1, v2, i2);
      top2_update(u2, j2, v1, i1, v2, i2);
    }
    if (l == 0) {
      s_red[wv][0] = v1; s_red[wv][1] = __int_as_float(i1);
      s_red[wv][2] = v2; s_red[wv][3] = __int_as_float(i2);
    }
    __syncthreads();
    if (t == 0) {
      float a1 = s_red[0][0]; int x1 = __float_as_int(s_red[0][1]);
      float a2 = s_red[0][2]; int x2 = __float_as_int(s_red[0][3]);
      #pragma unroll
      for (int e = 1; e < 4; ++e) {
        top2_update(s_red[e][0], __float_as_int(s_red[e][1]), a1, x1, a2, x2);
        top2_update(s_red[e][2], __float_as_int(s_red[e][3]), a1, x1, a2, x2);
      }
      float* cp = cand + (size_t)blk * 4;
      cp[0] = a1; cp[1] = __int_as_float(x1);
      cp[2] = a2; cp[3] = __int_as_float(x2);
    }
  }
}

// ---------------------------------------------------------------------------
// Rank+mask kernel: grid (B x 8). Each block redundantly merges the 144
// candidates -> top-8 (by bf16 Q), recomputes those 8 exactly in fp32,
// picks exact top-2 (jax tie rule: lower index), writes its mask slice.
// ---------------------------------------------------------------------------
__global__ __launch_bounds__(256) void rankmask_kernel(
    const float* __restrict__ O, const float* __restrict__ W1,
    const float* __restrict__ b1, const float* __restrict__ W2,
    const float* __restrict__ cand, float* __restrict__ mask)
{
  const int b   = blockIdx.x >> 3;
  const int cch = blockIdx.x & 7;
  const int t   = threadIdx.x;
  __shared__ float s_cv[144];
  __shared__ int   s_ci[144];
  __shared__ int   s_m[8];
  __shared__ int   s_ij[8][2];
  __shared__ float s_or[8][2][64];
  __shared__ float s_part[8][32];
  __shared__ int   s_k0, s_k1;

  if (t < 144) {
    const float* cp = cand + (size_t)(b * 72 + (t >> 1)) * 4;
    s_cv[t] = cp[(t & 1) * 2];
    s_ci[t] = __float_as_int(cp[(t & 1) * 2 + 1]);
  }
  __syncthreads();
  if (t < 144) {
    float v = s_cv[t]; int m = s_ci[t];
    int rank = 0;
    for (int e = 0; e < 144; ++e) {
      float u = s_cv[e]; int n = s_ci[e];
      rank += (u > v || (u == v && n < m)) ? 1 : 0;
    }
    if (rank < 8) s_m[rank] = m;
  }
  __syncthreads();
  if (t < 16) {
    int m = s_m[t >> 1];
    int i = 0, rem = m;
    while (rem >= Nn - 1 - i) { rem -= Nn - 1 - i; ++i; }
    int j = i + 1 + rem;
    s_ij[t >> 1][t & 1] = (t & 1) ? j : i;
  }
  __syncthreads();
  {
    int cc = t >> 5, rr = (t >> 4) & 1, c4 = (t & 15) * 4;
    int row = s_ij[cc][rr];
    *(float4*)&s_or[cc][rr][c4] = *(const float4*)&O[((size_t)b * Nn + row) * 64 + c4];
  }
  __syncthreads();
  {
    int cc = t >> 5, hh = t & 31, h2 = hh * 2;
    float z0 = b1[h2], z1 = b1[h2 + 1];
    #pragma unroll 8
    for (int d = 0; d < 64; ++d) {
      float oi = s_or[cc][0][d], oj = s_or[cc][1][d];
      float f3 = fabsf(oi - oj), f4 = oi * oj;
      float2 wa = *(const float2*)&W1[(d      ) * 64 + h2];
      float2 wb = *(const float2*)&W1[(64 + d ) * 64 + h2];
      float2 wc = *(const float2*)&W1[(128 + d) * 64 + h2];
      float2 wd = *(const float2*)&W1[(192 + d) * 64 + h2];
      z0 += oi * wa.x + oj * wb.x + f3 * wc.x + f4 * wd.x;
      z1 += oi * wa.y + oj * wb.y + f3 * wc.y + f4 * wd.y;
    }
    s_part[cc][hh] = fmaxf(z0, 0.f) * W2[h2] + fmaxf(z1, 0.f) * W2[h2 + 1];
  }
  __syncthreads();
  if (t == 0) {
    float v1 = -INFINITY, v2 = -INFINITY;
    int   i1 = 0x7fffffff, i2 = 0x7fffffff;
    for (int e = 0; e < 8; ++e) {
      float s = 0.f;
      for (int u = 0; u < 32; ++u) s += s_part[e][u];
      top2_update(s, s_m[e], v1, i1, v2, i2);
    }
    s_k0 = i1; s_k1 = i2;
  }
  __syncthreads();

  const int k0 = s_k0, k1 = s_k1;
  float* mb = mask + (size_t)b * Mm;
  const int m0 = cch * CHUNK;
  for (int m = m0 + t; m < m0 + CHUNK; m += 256)
    mb[m] = (m == k0 || m == k1) ? 1.0f : 0.0f;
}

extern "C" void kernel_launch(void* const* d_in, const int* in_sizes, int n_in,
                              void* d_out, int out_size, void* d_ws, size_t ws_size,
                              hipStream_t stream) {
  const float* O  = (const float*)d_in[0];
  const float* W1 = (const float*)d_in[1];
  const float* b1 = (const float*)d_in[2];
  const float* W2 = (const float*)d_in[3];
  const float* b2 = (const float*)d_in[4];

  float* Q    = (float*)d_out;
  float* mask = Q + (size_t)Bn * Mm;

  unsigned short* wtg = (unsigned short*)d_ws;                    // 32768 B
  float* cand = (float*)((char*)d_ws + 32768);                    // 18432 B

  prep_w1t<<<dim3(64), dim3(256), 0, stream>>>(W1, wtg);
  pair_kernel<<<dim3(Bn * 72), dim3(256), 0, stream>>>(O, b1, W2, b2, wtg, Q, cand);
  rankmask_kernel<<<dim3(Bn * 8), dim3(256), 0, stream>>>(O, W1, b1, W2, cand, mask);
}

// Round 8
// 85.114 us; speedup vs baseline: 2.0959x; 1.1473x over previous
//
#include <hip/hip_runtime.h>
#include <math.h>

#define Bn 16
#define Nn 256
#define Mm (Nn*(Nn-1)/2)   /* 32640 */
#define CHUNK 4080         /* Mm / 8 */

typedef __attribute__((ext_vector_type(8))) short bf16x8;
typedef __attribute__((ext_vector_type(4))) short short4v;
typedef __attribute__((ext_vector_type(4))) float f32x4;

typedef union { bf16x8 v; short s[8]; __bf16 h[8]; } F8;
typedef union { short4v v; __bf16 h[4]; } F4;

#define MFMA(acc, a, b) \
  acc = __builtin_amdgcn_mfma_f32_16x16x32_bf16((a), (b), (acc), 0, 0, 0)

__device__ __forceinline__ void top2_update(float v, int m,
    float& v1, int& i1, float& v2, int& i2)
{
  bool c1 = (v > v1) || (v == v1 && m < i1);
  bool c2 = (v > v2) || (v == v2 && m < i2);
  float nv2 = c1 ? v1 : (c2 ? v : v2);
  int   ni2 = c1 ? i1 : (c2 ? m : i2);
  v1 = c1 ? v : v1;  i1 = c1 ? m : i1;
  v2 = nv2;          i2 = ni2;
}

// ---------------------------------------------------------------------------
// Prep 1: W1 (256k x 64h f32) -> wtg bf16 [h][k] (64 x 256), RNE cast.
// ---------------------------------------------------------------------------
__global__ __launch_bounds__(256) void prep_w1t(
    const float* __restrict__ W1, unsigned short* __restrict__ wtg)
{
  const int h = blockIdx.x;      // 0..63
  const int k = threadIdx.x;     // 0..255
  __bf16 b = (__bf16)W1[k * 64 + h];
  wtg[h * 256 + k] = *(unsigned short*)&b;
}

// ---------------------------------------------------------------------------
// Prep 2: per (batch, 64-row tile): obg = bf16(O); A = O@W1a + b1 (f32);
// C = O@W1b (bf16). 64 blocks x 256 thr (4 waves), MFMA.
// ---------------------------------------------------------------------------
__global__ __launch_bounds__(256) void prep_ac(
    const float* __restrict__ O, const float* __restrict__ b1,
    const unsigned short* __restrict__ wtg,
    unsigned short* __restrict__ obg, float* __restrict__ Ag,
    unsigned short* __restrict__ Cgb)
{
  __shared__ __align__(16) unsigned short s_ob[64][72];
  const int t = threadIdx.x, l = t & 63, wv = t >> 6;
  const int lo = l & 15, g = l >> 4;
  const int b = blockIdx.x >> 2, rt = blockIdx.x & 3;
  const int r0 = rt * 64;
  const float* Ob = O + ((size_t)b * Nn + r0) * 64;

  #pragma unroll
  for (int p = 0; p < 4; ++p) {
    int v = t + p * 256;             // 1024 short4v groups
    int r = v >> 4, c4 = (v & 15) * 4;
    float4 x = ((const float4*)Ob)[v];
    F4 pk; pk.h[0] = (__bf16)x.x; pk.h[1] = (__bf16)x.y;
           pk.h[2] = (__bf16)x.z; pk.h[3] = (__bf16)x.w;
    *(short4v*)&s_ob[r][c4] = pk.v;
    *(short4v*)&obg[((size_t)b * Nn + r0 + r) * 64 + c4] = pk.v;
  }
  __syncthreads();

  // wave wv handles rows r0 + wv*16 .. +15, both halves (A then C)
  F8 aop[2];
  #pragma unroll
  for (int ks = 0; ks < 2; ++ks)
    aop[ks].v = *(const bf16x8*)&s_ob[wv * 16 + lo][ks * 32 + g * 8];

  #pragma unroll
  for (int half = 0; half < 2; ++half) {
    #pragma unroll
    for (int nf = 0; nf < 4; ++nf) {
      f32x4 ac = {0.f, 0.f, 0.f, 0.f};
      #pragma unroll
      for (int ks = 0; ks < 2; ++ks) {
        F8 bop; bop.v = *(const bf16x8*)&wtg[(nf * 16 + lo) * 256 + half * 64 + ks * 32 + g * 8];
        MFMA(ac, aop[ks].v, bop.v);
      }
      const int h = nf * 16 + lo;
      if (half == 0) {
        float bb = b1[h];
        #pragma unroll
        for (int r = 0; r < 4; ++r)
          Ag[((size_t)b * Nn + r0 + wv * 16 + g * 4 + r) * 64 + h] = ac[r] + bb;
      } else {
        #pragma unroll
        for (int r = 0; r < 4; ++r) {
          __bf16 cb = (__bf16)ac[r];
          Cgb[((size_t)b * Nn + r0 + wv * 16 + g * 4 + r) * 64 + h] = *(unsigned short*)&cb;
        }
      }
    }
  }
}

// ---------------------------------------------------------------------------
// Pair kernel: one block = (batch, 16x32 pair tile), 256 thr (4 waves).
// All shared tables precomputed: obg (bf16 O), Ag (A+b1, f32), Cgb (C, bf16).
// Pairwise W half staged in LDS (s_wt) so any register remat is a cheap
// ds_read, never HBM. Wave wv owns i-rows wv*4..+3; per (ii,jh): feature
// build (VALU) + 16 MFMA + relu/W2 epilogue + 2 shfl.
// LDS ~31 KB -> 5 blocks/CU.
// ---------------------------------------------------------------------------
__global__ __launch_bounds__(256, 3) void pair_kernel(
    const unsigned short* __restrict__ obg,
    const float* __restrict__ Ag,
    const unsigned short* __restrict__ Cgb,
    const float* __restrict__ W2,
    const float* __restrict__ b2,
    const unsigned short* __restrict__ wtg,
    float* __restrict__ Q,
    float* __restrict__ cand)
{
  __shared__ __align__(16) unsigned short s_wt[64][136]; // pairwise W^T bf16 [h][k-128]
  __shared__ __align__(16) unsigned short s_oi[16][72];
  __shared__ __align__(16) unsigned short s_oj[32][72];
  __shared__ float s_A [16][68];  // A[i][h] (+b1)
  __shared__ float s_q [16][36];
  __shared__ float s_w2[64];
  __shared__ float s_red[4][4];

  const int t  = threadIdx.x;
  const int l  = t & 63, wv = t >> 6;
  const int lo = l & 15, g = l >> 4;

  const int blk   = blockIdx.x;
  const int batch = blk / 72;
  int tl          = blk % 72;
  int a = 0;
  while (tl >= 8 - (a >> 1)) { tl -= 8 - (a >> 1); ++a; }
  const int c   = (a >> 1) + tl;
  const int ti0 = a * 16, tj0 = c * 32;

  // ---- stage: W pairwise half (16 KB), O tiles (bf16 copy), A rows ----
  {
    const int h = t >> 2, kq = (t & 3) * 32;
    #pragma unroll
    for (int q = 0; q < 4; ++q) {
      *(bf16x8*)&s_wt[h][kq + q * 8] =
          *(const bf16x8*)&wtg[h * 256 + 128 + kq + q * 8];
    }
  }
  {
    int r = t >> 4, c4 = (t & 15) * 4;
    *(short4v*)&s_oi[r][c4] =
        *(const short4v*)&obg[((size_t)batch * Nn + ti0 + r) * 64 + c4];
    *(f32x4*)&s_A[r][c4] =
        *(const f32x4*)&Ag[((size_t)batch * Nn + ti0 + r) * 64 + c4];
    #pragma unroll
    for (int p = 0; p < 2; ++p) {
      int v = t + p * 256;
      int rj = v >> 4, cj = (v & 15) * 4;
      *(short4v*)&s_oj[rj][cj] =
          *(const short4v*)&obg[((size_t)batch * Nn + tj0 + rj) * 64 + cj];
    }
    if (t < 64) s_w2[t] = W2[t];
  }
  __syncthreads();

  // ---- hoists: W frags (from LDS: remat-safe), oj bf16, C-init bf16 ----
  F8 bfr[4][4];   // [ks][nf]
  #pragma unroll
  for (int ks = 0; ks < 4; ++ks)
    #pragma unroll
    for (int nf = 0; nf < 4; ++nf)
      bfr[ks][nf].v = *(const bf16x8*)&s_wt[nf * 16 + lo][ks * 32 + g * 8];

  F8 ojb[2][2];
  #pragma unroll
  for (int jh = 0; jh < 2; ++jh) {
    ojb[jh][0].v = *(const bf16x8*)&s_oj[jh * 16 + lo][g * 8];
    ojb[jh][1].v = *(const bf16x8*)&s_oj[jh * 16 + lo][32 + g * 8];
  }
  F4 cinb[2][4];  // C[j= tj0+jh*16+lo][nf*16+g*4 ..+3] bf16 (global, L2-hot)
  #pragma unroll
  for (int jh = 0; jh < 2; ++jh)
    #pragma unroll
    for (int nf = 0; nf < 4; ++nf)
      cinb[jh][nf].v = *(const short4v*)
          &Cgb[((size_t)batch * Nn + tj0 + jh * 16 + lo) * 64 + nf * 16 + g * 4];

  // ---- main loop: wave owns i-rows wv*4 .. wv*4+3 ----
  for (int ii = 0; ii < 4; ++ii) {
    const int iL = wv * 4 + ii;

    float oiv[16];
    {
      F8 u0, u1;
      u0.v = *(const bf16x8*)&s_oi[iL][g * 8];
      u1.v = *(const bf16x8*)&s_oi[iL][32 + g * 8];
      #pragma unroll
      for (int e = 0; e < 8; ++e) {
        oiv[e]     = (float)u0.h[e];
        oiv[8 + e] = (float)u1.h[e];
      }
    }
    f32x4 as4[4];
    #pragma unroll
    for (int nf = 0; nf < 4; ++nf)
      as4[nf] = *(const f32x4*)&s_A[iL][nf * 16 + g * 4];

    #pragma unroll
    for (int jh = 0; jh < 2; ++jh) {
      F8 fb0, fb1, fb2, fb3;
      #pragma unroll
      for (int e = 0; e < 8; ++e) {
        float p0 = (float)ojb[jh][0].h[e];
        float p1 = (float)ojb[jh][1].h[e];
        fb0.h[e] = (__bf16)fabsf(oiv[e]     - p0);
        fb1.h[e] = (__bf16)fabsf(oiv[8 + e] - p1);
        fb2.h[e] = (__bf16)(oiv[e]     * p0);
        fb3.h[e] = (__bf16)(oiv[8 + e] * p1);
      }

      f32x4 acc[4] = { as4[0], as4[1], as4[2], as4[3] };
      #pragma unroll
      for (int nf = 0; nf < 4; ++nf) {
        MFMA(acc[nf], bfr[0][nf].v, fb0.v);
        MFMA(acc[nf], bfr[1][nf].v, fb1.v);
        MFMA(acc[nf], bfr[2][nf].v, fb2.v);
        MFMA(acc[nf], bfr[3][nf].v, fb3.v);
      }

      // epilogue: + C (bf16->f32), relu, W2 dot, reduce over g
      float part = 0.f;
      #pragma unroll
      for (int nf = 0; nf < 4; ++nf) {
        #pragma unroll
        for (int r = 0; r < 4; ++r) {
          float z = acc[nf][r] + (float)cinb[jh][nf].h[r];
          part = fmaf(fmaxf(z, 0.f), s_w2[nf * 16 + g * 4 + r], part);
        }
      }
      part += __shfl_xor(part, 16);
      part += __shfl_xor(part, 32);
      if (g == 0) s_q[iL][jh * 16 + lo] = part;
    }
  }
  __syncthreads();

  // ---- final: Q store + block top-2 candidates ----
  {
    const float b2v = b2[0];
    const int e0 = t * 2;
    const int row = e0 >> 5, col0 = e0 & 31;
    const int i = ti0 + row;
    float v1 = -INFINITY, v2 = -INFINITY;
    int   i1 = 0x7fffffff, i2 = 0x7fffffff;
    const int mbase = i * (Nn - 1) - (i * (i - 1)) / 2 - i - 1;
    #pragma unroll
    for (int e = 0; e < 2; ++e) {
      const int col = col0 + e;
      const int j = tj0 + col;
      const float qv = s_q[row][col] + b2v;
      if (j > i) {
        const int m = mbase + j;
        Q[(size_t)batch * Mm + m] = qv;
        top2_update(qv, m, v1, i1, v2, i2);
      }
    }
    #pragma unroll
    for (int s = 1; s < 64; s <<= 1) {
      float u1 = __shfl_xor(v1, s); int j1 = __shfl_xor(i1, s);
      float u2 = __shfl_xor(v2, s); int j2 = __shfl_xor(i2, s);
      top2_update(u1, j1, v1, i1, v2, i2);
      top2_update(u2, j2, v1, i1, v2, i2);
    }
    if (l == 0) {
      s_red[wv][0] = v1; s_red[wv][1] = __int_as_float(i1);
      s_red[wv][2] = v2; s_red[wv][3] = __int_as_float(i2);
    }
    __syncthreads();
    if (t == 0) {
      float a1 = s_red[0][0]; int x1 = __float_as_int(s_red[0][1]);
      float a2 = s_red[0][2]; int x2 = __float_as_int(s_red[0][3]);
      #pragma unroll
      for (int e = 1; e < 4; ++e) {
        top2_update(s_red[e][0], __float_as_int(s_red[e][1]), a1, x1, a2, x2);
        top2_update(s_red[e][2], __float_as_int(s_red[e][3]), a1, x1, a2, x2);
      }
      float* cp = cand + (size_t)blk * 4;
      cp[0] = a1; cp[1] = __int_as_float(x1);
      cp[2] = a2; cp[3] = __int_as_float(x2);
    }
  }
}

// ---------------------------------------------------------------------------
// Rank+mask kernel: grid (B x 8). Each block redundantly merges the 144
// candidates -> top-8 (by bf16 Q), recomputes those 8 exactly in fp32,
// picks exact top-2 (jax tie rule: lower index), writes its mask slice.
// ---------------------------------------------------------------------------
__global__ __launch_bounds__(256) void rankmask_kernel(
    const float* __restrict__ O, const float* __restrict__ W1,
    const float* __restrict__ b1, const float* __restrict__ W2,
    const float* __restrict__ cand, float* __restrict__ mask)
{
  const int b   = blockIdx.x >> 3;
  const int cch = blockIdx.x & 7;
  const int t   = threadIdx.x;
  __shared__ float s_cv[144];
  __shared__ int   s_ci[144];
  __shared__ int   s_m[8];
  __shared__ int   s_ij[8][2];
  __shared__ float s_or[8][2][64];
  __shared__ float s_part[8][32];
  __shared__ int   s_k0, s_k1;

  if (t < 144) {
    const float* cp = cand + (size_t)(b * 72 + (t >> 1)) * 4;
    s_cv[t] = cp[(t & 1) * 2];
    s_ci[t] = __float_as_int(cp[(t & 1) * 2 + 1]);
  }
  __syncthreads();
  if (t < 144) {
    float v = s_cv[t]; int m = s_ci[t];
    int rank = 0;
    for (int e = 0; e < 144; ++e) {
      float u = s_cv[e]; int n = s_ci[e];
      rank += (u > v || (u == v && n < m)) ? 1 : 0;
    }
    if (rank < 8) s_m[rank] = m;
  }
  __syncthreads();
  if (t < 16) {
    int m = s_m[t >> 1];
    int i = 0, rem = m;
    while (rem >= Nn - 1 - i) { rem -= Nn - 1 - i; ++i; }
    int j = i + 1 + rem;
    s_ij[t >> 1][t & 1] = (t & 1) ? j : i;
  }
  __syncthreads();
  {
    int cc = t >> 5, rr = (t >> 4) & 1, c4 = (t & 15) * 4;
    int row = s_ij[cc][rr];
    *(float4*)&s_or[cc][rr][c4] = *(const float4*)&O[((size_t)b * Nn + row) * 64 + c4];
  }
  __syncthreads();
  {
    int cc = t >> 5, hh = t & 31, h2 = hh * 2;
    float z0 = b1[h2], z1 = b1[h2 + 1];
    #pragma unroll 8
    for (int d = 0; d < 64; ++d) {
      float oi = s_or[cc][0][d], oj = s_or[cc][1][d];
      float f3 = fabsf(oi - oj), f4 = oi * oj;
      float2 wa = *(const float2*)&W1[(d      ) * 64 + h2];
      float2 wb = *(const float2*)&W1[(64 + d ) * 64 + h2];
      float2 wc = *(const float2*)&W1[(128 + d) * 64 + h2];
      float2 wd = *(const float2*)&W1[(192 + d) * 64 + h2];
      z0 += oi * wa.x + oj * wb.x + f3 * wc.x + f4 * wd.x;
      z1 += oi * wa.y + oj * wb.y + f3 * wc.y + f4 * wd.y;
    }
    s_part[cc][hh] = fmaxf(z0, 0.f) * W2[h2] + fmaxf(z1, 0.f) * W2[h2 + 1];
  }
  __syncthreads();
  if (t == 0) {
    float v1 = -INFINITY, v2 = -INFINITY;
    int   i1 = 0x7fffffff, i2 = 0x7fffffff;
    for (int e = 0; e < 8; ++e) {
      float s = 0.f;
      for (int u = 0; u < 32; ++u) s += s_part[e][u];
      top2_update(s, s_m[e], v1, i1, v2, i2);
    }
    s_k0 = i1; s_k1 = i2;
  }
  __syncthreads();

  const int k0 = s_k0, k1 = s_k1;
  float* mb = mask + (size_t)b * Mm;
  const int m0 = cch * CHUNK;
  for (int m = m0 + t; m < m0 + CHUNK; m += 256)
    mb[m] = (m == k0 || m == k1) ? 1.0f : 0.0f;
}

extern "C" void kernel_launch(void* const* d_in, const int* in_sizes, int n_in,
                              void* d_out, int out_size, void* d_ws, size_t ws_size,
                              hipStream_t stream) {
  const float* O  = (const float*)d_in[0];
  const float* W1 = (const float*)d_in[1];
  const float* b1 = (const float*)d_in[2];
  const float* W2 = (const float*)d_in[3];
  const float* b2 = (const float*)d_in[4];

  float* Q    = (float*)d_out;
  float* mask = Q + (size_t)Bn * Mm;

  char* ws = (char*)d_ws;
  unsigned short* wtg = (unsigned short*)ws;                  // 32768 B
  unsigned short* obg = (unsigned short*)(ws + 32768);        // 524288 B
  float*          Ag  = (float*)(ws + 32768 + 524288);        // 4194304 B? no: 16*256*64*4 = 1048576 B
  unsigned short* Cgb = (unsigned short*)(ws + 32768 + 524288 + 1048576);  // 524288 B
  float*          cand = (float*)(ws + 32768 + 524288 + 1048576 + 524288); // 18432 B

  prep_w1t<<<dim3(64), dim3(256), 0, stream>>>(W1, wtg);
  prep_ac<<<dim3(Bn * 4), dim3(256), 0, stream>>>(O, b1, wtg, obg, Ag, Cgb);
  pair_kernel<<<dim3(Bn * 72), dim3(256), 0, stream>>>(obg, Ag, Cgb, W2, b2, wtg, Q, cand);
  rankmask_kernel<<<dim3(Bn * 8), dim3(256), 0, stream>>>(O, W1, b1, W2, cand, mask);
}

// Round 9
// 77.897 us; speedup vs baseline: 2.2901x; 1.0927x over previous
//
#include <hip/hip_runtime.h>
#include <math.h>

#define Bn 16
#define Nn 256
#define Mm (Nn*(Nn-1)/2)   /* 32640 */
#define CHUNK 4080         /* Mm / 8 */

typedef __attribute__((ext_vector_type(8))) short bf16x8;
typedef __attribute__((ext_vector_type(4))) short short4v;
typedef __attribute__((ext_vector_type(4))) float f32x4;

typedef union { bf16x8 v; short s[8]; __bf16 h[8]; } F8;
typedef union { short4v v; __bf16 h[4]; } F4;

#define MFMA(acc, a, b) \
  acc = __builtin_amdgcn_mfma_f32_16x16x32_bf16((a), (b), (acc), 0, 0, 0)

__device__ __forceinline__ void top2_update(float v, int m,
    float& v1, int& i1, float& v2, int& i2)
{
  bool c1 = (v > v1) || (v == v1 && m < i1);
  bool c2 = (v > v2) || (v == v2 && m < i2);
  float nv2 = c1 ? v1 : (c2 ? v : v2);
  int   ni2 = c1 ? i1 : (c2 ? m : i2);
  v1 = c1 ? v : v1;  i1 = c1 ? m : i1;
  v2 = nv2;          i2 = ni2;
}

// ---------------------------------------------------------------------------
// Prep 1: W1 (256k x 64h f32) -> wtg bf16 [h][k] (64 x 256), RNE cast.
// ---------------------------------------------------------------------------
__global__ __launch_bounds__(256) void prep_w1t(
    const float* __restrict__ W1, unsigned short* __restrict__ wtg)
{
  const int h = blockIdx.x;      // 0..63
  const int k = threadIdx.x;     // 0..255
  __bf16 b = (__bf16)W1[k * 64 + h];
  wtg[h * 256 + k] = *(unsigned short*)&b;
}

// ---------------------------------------------------------------------------
// Prep 2: per (batch, 64-row tile): obg = bf16(O); A = O@W1a + b1 (f32);
// C = O@W1b (bf16). 64 blocks x 256 thr (4 waves), MFMA.
// ---------------------------------------------------------------------------
__global__ __launch_bounds__(256) void prep_ac(
    const float* __restrict__ O, const float* __restrict__ b1,
    const unsigned short* __restrict__ wtg,
    unsigned short* __restrict__ obg, float* __restrict__ Ag,
    unsigned short* __restrict__ Cgb)
{
  __shared__ __align__(16) unsigned short s_ob[64][72];
  const int t = threadIdx.x, l = t & 63, wv = t >> 6;
  const int lo = l & 15, g = l >> 4;
  const int b = blockIdx.x >> 2, rt = blockIdx.x & 3;
  const int r0 = rt * 64;
  const float* Ob = O + ((size_t)b * Nn + r0) * 64;

  #pragma unroll
  for (int p = 0; p < 4; ++p) {
    int v = t + p * 256;             // 1024 short4v groups
    int r = v >> 4, c4 = (v & 15) * 4;
    float4 x = ((const float4*)Ob)[v];
    F4 pk; pk.h[0] = (__bf16)x.x; pk.h[1] = (__bf16)x.y;
           pk.h[2] = (__bf16)x.z; pk.h[3] = (__bf16)x.w;
    *(short4v*)&s_ob[r][c4] = pk.v;
    *(short4v*)&obg[((size_t)b * Nn + r0 + r) * 64 + c4] = pk.v;
  }
  __syncthreads();

  // wave wv handles rows r0 + wv*16 .. +15, both halves (A then C)
  F8 aop[2];
  #pragma unroll
  for (int ks = 0; ks < 2; ++ks)
    aop[ks].v = *(const bf16x8*)&s_ob[wv * 16 + lo][ks * 32 + g * 8];

  #pragma unroll
  for (int half = 0; half < 2; ++half) {
    #pragma unroll
    for (int nf = 0; nf < 4; ++nf) {
      f32x4 ac = {0.f, 0.f, 0.f, 0.f};
      #pragma unroll
      for (int ks = 0; ks < 2; ++ks) {
        F8 bop; bop.v = *(const bf16x8*)&wtg[(nf * 16 + lo) * 256 + half * 64 + ks * 32 + g * 8];
        MFMA(ac, aop[ks].v, bop.v);
      }
      const int h = nf * 16 + lo;
      if (half == 0) {
        float bb = b1[h];
        #pragma unroll
        for (int r = 0; r < 4; ++r)
          Ag[((size_t)b * Nn + r0 + wv * 16 + g * 4 + r) * 64 + h] = ac[r] + bb;
      } else {
        #pragma unroll
        for (int r = 0; r < 4; ++r) {
          __bf16 cb = (__bf16)ac[r];
          Cgb[((size_t)b * Nn + r0 + wv * 16 + g * 4 + r) * 64 + h] = *(unsigned short*)&cb;
        }
      }
    }
  }
}

// ---------------------------------------------------------------------------
// Pair kernel: one block = (batch, 16x32 pair tile), 256 thr (4 waves).
// XCD-aware decode: hardware assigns wg n -> XCD (n % 8); we map blk so
// XCD x serves only batches {2x, 2x+1}. Per-XCD L2 working set: wtg 32KB +
// 2 x 128KB batch tables -> staging reads are L2 hits (was: 16.7MB HBM).
// All shared tables precomputed: obg (bf16 O), Ag (A+b1, f32), Cgb (C, bf16).
// Pairwise W half staged in LDS (s_wt) so register remat is ds_read, not HBM.
// ---------------------------------------------------------------------------
__global__ __launch_bounds__(256, 3) void pair_kernel(
    const unsigned short* __restrict__ obg,
    const float* __restrict__ Ag,
    const unsigned short* __restrict__ Cgb,
    const float* __restrict__ W2,
    const float* __restrict__ b2,
    const unsigned short* __restrict__ wtg,
    float* __restrict__ Q,
    float* __restrict__ cand)
{
  __shared__ __align__(16) unsigned short s_wt[64][136]; // pairwise W^T bf16 [h][k-128]
  __shared__ __align__(16) unsigned short s_oi[16][72];
  __shared__ __align__(16) unsigned short s_oj[32][72];
  __shared__ float s_A [16][68];  // A[i][h] (+b1)
  __shared__ float s_q [16][36];
  __shared__ float s_w2[64];
  __shared__ float s_red[4][4];

  const int t  = threadIdx.x;
  const int l  = t & 63, wv = t >> 6;
  const int lo = l & 15, g = l >> 4;

  const int blk    = blockIdx.x;
  const int within = blk >> 3;                    // 0..143
  const int batch  = (blk & 7) * 2 + within / 72; // XCD (blk%8) -> batches 2x,2x+1
  int tl           = within % 72;
  int a = 0;
  while (tl >= 8 - (a >> 1)) { tl -= 8 - (a >> 1); ++a; }
  const int c   = (a >> 1) + tl;
  const int ti0 = a * 16, tj0 = c * 32;

  // ---- stage: W pairwise half (16 KB), O tiles (bf16 copy), A rows ----
  {
    const int h = t >> 2, kq = (t & 3) * 32;
    #pragma unroll
    for (int q = 0; q < 4; ++q) {
      *(bf16x8*)&s_wt[h][kq + q * 8] =
          *(const bf16x8*)&wtg[h * 256 + 128 + kq + q * 8];
    }
  }
  {
    int r = t >> 4, c4 = (t & 15) * 4;
    *(short4v*)&s_oi[r][c4] =
        *(const short4v*)&obg[((size_t)batch * Nn + ti0 + r) * 64 + c4];
    *(f32x4*)&s_A[r][c4] =
        *(const f32x4*)&Ag[((size_t)batch * Nn + ti0 + r) * 64 + c4];
    #pragma unroll
    for (int p = 0; p < 2; ++p) {
      int v = t + p * 256;
      int rj = v >> 4, cj = (v & 15) * 4;
      *(short4v*)&s_oj[rj][cj] =
          *(const short4v*)&obg[((size_t)batch * Nn + tj0 + rj) * 64 + cj];
    }
    if (t < 64) s_w2[t] = W2[t];
  }
  __syncthreads();

  // ---- hoists: W frags (from LDS: remat-safe), oj bf16, C-init bf16 ----
  F8 bfr[4][4];   // [ks][nf]
  #pragma unroll
  for (int ks = 0; ks < 4; ++ks)
    #pragma unroll
    for (int nf = 0; nf < 4; ++nf)
      bfr[ks][nf].v = *(const bf16x8*)&s_wt[nf * 16 + lo][ks * 32 + g * 8];

  F8 ojb[2][2];
  #pragma unroll
  for (int jh = 0; jh < 2; ++jh) {
    ojb[jh][0].v = *(const bf16x8*)&s_oj[jh * 16 + lo][g * 8];
    ojb[jh][1].v = *(const bf16x8*)&s_oj[jh * 16 + lo][32 + g * 8];
  }
  F4 cinb[2][4];  // C[j= tj0+jh*16+lo][nf*16+g*4 ..+3] bf16 (global, L2-hot)
  #pragma unroll
  for (int jh = 0; jh < 2; ++jh)
    #pragma unroll
    for (int nf = 0; nf < 4; ++nf)
      cinb[jh][nf].v = *(const short4v*)
          &Cgb[((size_t)batch * Nn + tj0 + jh * 16 + lo) * 64 + nf * 16 + g * 4];

  // ---- main loop: wave owns i-rows wv*4 .. wv*4+3 ----
  for (int ii = 0; ii < 4; ++ii) {
    const int iL = wv * 4 + ii;

    float oiv[16];
    {
      F8 u0, u1;
      u0.v = *(const bf16x8*)&s_oi[iL][g * 8];
      u1.v = *(const bf16x8*)&s_oi[iL][32 + g * 8];
      #pragma unroll
      for (int e = 0; e < 8; ++e) {
        oiv[e]     = (float)u0.h[e];
        oiv[8 + e] = (float)u1.h[e];
      }
    }
    f32x4 as4[4];
    #pragma unroll
    for (int nf = 0; nf < 4; ++nf)
      as4[nf] = *(const f32x4*)&s_A[iL][nf * 16 + g * 4];

    #pragma unroll
    for (int jh = 0; jh < 2; ++jh) {
      F8 fb0, fb1, fb2, fb3;
      #pragma unroll
      for (int e = 0; e < 8; ++e) {
        float p0 = (float)ojb[jh][0].h[e];
        float p1 = (float)ojb[jh][1].h[e];
        fb0.h[e] = (__bf16)fabsf(oiv[e]     - p0);
        fb1.h[e] = (__bf16)fabsf(oiv[8 + e] - p1);
        fb2.h[e] = (__bf16)(oiv[e]     * p0);
        fb3.h[e] = (__bf16)(oiv[8 + e] * p1);
      }

      f32x4 acc[4] = { as4[0], as4[1], as4[2], as4[3] };
      #pragma unroll
      for (int nf = 0; nf < 4; ++nf) {
        MFMA(acc[nf], bfr[0][nf].v, fb0.v);
        MFMA(acc[nf], bfr[1][nf].v, fb1.v);
        MFMA(acc[nf], bfr[2][nf].v, fb2.v);
        MFMA(acc[nf], bfr[3][nf].v, fb3.v);
      }

      // epilogue: + C (bf16->f32), relu, W2 dot, reduce over g
      float part = 0.f;
      #pragma unroll
      for (int nf = 0; nf < 4; ++nf) {
        #pragma unroll
        for (int r = 0; r < 4; ++r) {
          float z = acc[nf][r] + (float)cinb[jh][nf].h[r];
          part = fmaf(fmaxf(z, 0.f), s_w2[nf * 16 + g * 4 + r], part);
        }
      }
      part += __shfl_xor(part, 16);
      part += __shfl_xor(part, 32);
      if (g == 0) s_q[iL][jh * 16 + lo] = part;
    }
  }
  __syncthreads();

  // ---- final: Q store + block top-2 candidates ----
  {
    const float b2v = b2[0];
    const int e0 = t * 2;
    const int row = e0 >> 5, col0 = e0 & 31;
    const int i = ti0 + row;
    float v1 = -INFINITY, v2 = -INFINITY;
    int   i1 = 0x7fffffff, i2 = 0x7fffffff;
    const int mbase = i * (Nn - 1) - (i * (i - 1)) / 2 - i - 1;
    #pragma unroll
    for (int e = 0; e < 2; ++e) {
      const int col = col0 + e;
      const int j = tj0 + col;
      const float qv = s_q[row][col] + b2v;
      if (j > i) {
        const int m = mbase + j;
        Q[(size_t)batch * Mm + m] = qv;
        top2_update(qv, m, v1, i1, v2, i2);
      }
    }
    #pragma unroll
    for (int s = 1; s < 64; s <<= 1) {
      float u1 = __shfl_xor(v1, s); int j1 = __shfl_xor(i1, s);
      float u2 = __shfl_xor(v2, s); int j2 = __shfl_xor(i2, s);
      top2_update(u1, j1, v1, i1, v2, i2);
      top2_update(u2, j2, v1, i1, v2, i2);
    }
    if (l == 0) {
      s_red[wv][0] = v1; s_red[wv][1] = __int_as_float(i1);
      s_red[wv][2] = v2; s_red[wv][3] = __int_as_float(i2);
    }
    __syncthreads();
    if (t == 0) {
      float a1 = s_red[0][0]; int x1 = __float_as_int(s_red[0][1]);
      float a2 = s_red[0][2]; int x2 = __float_as_int(s_red[0][3]);
      #pragma unroll
      for (int e = 1; e < 4; ++e) {
        top2_update(s_red[e][0], __float_as_int(s_red[e][1]), a1, x1, a2, x2);
        top2_update(s_red[e][2], __float_as_int(s_red[e][3]), a1, x1, a2, x2);
      }
      // cand indexed by (batch, tile) for rankmask
      float* cp = cand + ((size_t)batch * 72 + within % 72) * 4;
      cp[0] = a1; cp[1] = __int_as_float(x1);
      cp[2] = a2; cp[3] = __int_as_float(x2);
    }
  }
}

// ---------------------------------------------------------------------------
// Rank+mask kernel: grid (B x 8). Each block redundantly merges the 144
// candidates -> top-8 (by bf16 Q), recomputes those 8 exactly in fp32,
// picks exact top-2 (jax tie rule: lower index), writes its mask slice.
// ---------------------------------------------------------------------------
__global__ __launch_bounds__(256) void rankmask_kernel(
    const float* __restrict__ O, const float* __restrict__ W1,
    const float* __restrict__ b1, const float* __restrict__ W2,
    const float* __restrict__ cand, float* __restrict__ mask)
{
  const int b   = blockIdx.x >> 3;
  const int cch = blockIdx.x & 7;
  const int t   = threadIdx.x;
  __shared__ float s_cv[144];
  __shared__ int   s_ci[144];
  __shared__ int   s_m[8];
  __shared__ int   s_ij[8][2];
  __shared__ float s_or[8][2][64];
  __shared__ float s_part[8][32];
  __shared__ int   s_k0, s_k1;

  if (t < 144) {
    const float* cp = cand + (size_t)(b * 72 + (t >> 1)) * 4;
    s_cv[t] = cp[(t & 1) * 2];
    s_ci[t] = __float_as_int(cp[(t & 1) * 2 + 1]);
  }
  __syncthreads();
  if (t < 144) {
    float v = s_cv[t]; int m = s_ci[t];
    int rank = 0;
    for (int e = 0; e < 144; ++e) {
      float u = s_cv[e]; int n = s_ci[e];
      rank += (u > v || (u == v && n < m)) ? 1 : 0;
    }
    if (rank < 8) s_m[rank] = m;
  }
  __syncthreads();
  if (t < 16) {
    int m = s_m[t >> 1];
    int i = 0, rem = m;
    while (rem >= Nn - 1 - i) { rem -= Nn - 1 - i; ++i; }
    int j = i + 1 + rem;
    s_ij[t >> 1][t & 1] = (t & 1) ? j : i;
  }
  __syncthreads();
  {
    int cc = t >> 5, rr = (t >> 4) & 1, c4 = (t & 15) * 4;
    int row = s_ij[cc][rr];
    *(float4*)&s_or[cc][rr][c4] = *(const float4*)&O[((size_t)b * Nn + row) * 64 + c4];
  }
  __syncthreads();
  {
    int cc = t >> 5, hh = t & 31, h2 = hh * 2;
    float z0 = b1[h2], z1 = b1[h2 + 1];
    #pragma unroll 8
    for (int d = 0; d < 64; ++d) {
      float oi = s_or[cc][0][d], oj = s_or[cc][1][d];
      float f3 = fabsf(oi - oj), f4 = oi * oj;
      float2 wa = *(const float2*)&W1[(d      ) * 64 + h2];
      float2 wb = *(const float2*)&W1[(64 + d ) * 64 + h2];
      float2 wc = *(const float2*)&W1[(128 + d) * 64 + h2];
      float2 wd = *(const float2*)&W1[(192 + d) * 64 + h2];
      z0 += oi * wa.x + oj * wb.x + f3 * wc.x + f4 * wd.x;
      z1 += oi * wa.y + oj * wb.y + f3 * wc.y + f4 * wd.y;
    }
    s_part[cc][hh] = fmaxf(z0, 0.f) * W2[h2] + fmaxf(z1, 0.f) * W2[h2 + 1];
  }
  __syncthreads();
  if (t == 0) {
    float v1 = -INFINITY, v2 = -INFINITY;
    int   i1 = 0x7fffffff, i2 = 0x7fffffff;
    for (int e = 0; e < 8; ++e) {
      float s = 0.f;
      for (int u = 0; u < 32; ++u) s += s_part[e][u];
      top2_update(s, s_m[e], v1, i1, v2, i2);
    }
    s_k0 = i1; s_k1 = i2;
  }
  __syncthreads();

  const int k0 = s_k0, k1 = s_k1;
  float* mb = mask + (size_t)b * Mm;
  const int m0 = cch * CHUNK;
  for (int m = m0 + t; m < m0 + CHUNK; m += 256)
    mb[m] = (m == k0 || m == k1) ? 1.0f : 0.0f;
}

extern "C" void kernel_launch(void* const* d_in, const int* in_sizes, int n_in,
                              void* d_out, int out_size, void* d_ws, size_t ws_size,
                              hipStream_t stream) {
  const float* O  = (const float*)d_in[0];
  const float* W1 = (const float*)d_in[1];
  const float* b1 = (const float*)d_in[2];
  const float* W2 = (const float*)d_in[3];
  const float* b2 = (const float*)d_in[4];

  float* Q    = (float*)d_out;
  float* mask = Q + (size_t)Bn * Mm;

  char* ws = (char*)d_ws;
  unsigned short* wtg = (unsigned short*)ws;                  // 32768 B
  unsigned short* obg = (unsigned short*)(ws + 32768);        // 524288 B
  float*          Ag  = (float*)(ws + 32768 + 524288);        // 1048576 B
  unsigned short* Cgb = (unsigned short*)(ws + 32768 + 524288 + 1048576);  // 524288 B
  float*          cand = (float*)(ws + 32768 + 524288 + 1048576 + 524288); // 18432 B

  prep_w1t<<<dim3(64), dim3(256), 0, stream>>>(W1, wtg);
  prep_ac<<<dim3(Bn * 4), dim3(256), 0, stream>>>(O, b1, wtg, obg, Ag, Cgb);
  pair_kernel<<<dim3(Bn * 72), dim3(256), 0, stream>>>(obg, Ag, Cgb, W2, b2, wtg, Q, cand);
  rankmask_kernel<<<dim3(Bn * 8), dim3(256), 0, stream>>>(O, W1, b1, W2, cand, mask);
}

// Round 10
// 61.634 us; speedup vs baseline: 2.8944x; 1.2639x over previous
//
#include <hip/hip_runtime.h>
#include <math.h>

#define Bn 16
#define Nn 256
#define Mm (Nn*(Nn-1)/2)   /* 32640 */
#define CHUNK 4080         /* Mm / 8 */

typedef __attribute__((ext_vector_type(8))) short bf16x8;
typedef __attribute__((ext_vector_type(4))) short short4v;
typedef __attribute__((ext_vector_type(4))) float f32x4;

typedef union { bf16x8 v; short s[8]; __bf16 h[8]; } F8;
typedef union { short4v v; __bf16 h[4]; } F4;

#define MFMA(acc, a, b) \
  acc = __builtin_amdgcn_mfma_f32_16x16x32_bf16((a), (b), (acc), 0, 0, 0)

__device__ __forceinline__ void top2_update(float v, int m,
    float& v1, int& i1, float& v2, int& i2)
{
  bool c1 = (v > v1) || (v == v1 && m < i1);
  bool c2 = (v > v2) || (v == v2 && m < i2);
  float nv2 = c1 ? v1 : (c2 ? v : v2);
  int   ni2 = c1 ? i1 : (c2 ? m : i2);
  v1 = c1 ? v : v1;  i1 = c1 ? m : i1;
  v2 = nv2;          i2 = ni2;
}

// ---------------------------------------------------------------------------
// Prep 1: W1 (256k x 64h f32) -> wtg bf16 [h][k] (64 x 256), RNE cast.
// ---------------------------------------------------------------------------
__global__ __launch_bounds__(256) void prep_w1t(
    const float* __restrict__ W1, unsigned short* __restrict__ wtg)
{
  const int h = blockIdx.x;      // 0..63
  const int k = threadIdx.x;     // 0..255
  __bf16 b = (__bf16)W1[k * 64 + h];
  wtg[h * 256 + k] = *(unsigned short*)&b;
}

// ---------------------------------------------------------------------------
// Prep 2: per (batch, 64-row tile): obg = bf16(O); A = O@W1a + b1 (f32);
// C = O@W1b (bf16). 64 blocks x 256 thr (4 waves), MFMA.
// ---------------------------------------------------------------------------
__global__ __launch_bounds__(256) void prep_ac(
    const float* __restrict__ O, const float* __restrict__ b1,
    const unsigned short* __restrict__ wtg,
    unsigned short* __restrict__ obg, float* __restrict__ Ag,
    unsigned short* __restrict__ Cgb)
{
  __shared__ __align__(16) unsigned short s_ob[64][72];
  const int t = threadIdx.x, l = t & 63, wv = t >> 6;
  const int lo = l & 15, g = l >> 4;
  const int b = blockIdx.x >> 2, rt = blockIdx.x & 3;
  const int r0 = rt * 64;
  const float* Ob = O + ((size_t)b * Nn + r0) * 64;

  #pragma unroll
  for (int p = 0; p < 4; ++p) {
    int v = t + p * 256;             // 1024 short4v groups
    int r = v >> 4, c4 = (v & 15) * 4;
    float4 x = ((const float4*)Ob)[v];
    F4 pk; pk.h[0] = (__bf16)x.x; pk.h[1] = (__bf16)x.y;
           pk.h[2] = (__bf16)x.z; pk.h[3] = (__bf16)x.w;
    *(short4v*)&s_ob[r][c4] = pk.v;
    *(short4v*)&obg[((size_t)b * Nn + r0 + r) * 64 + c4] = pk.v;
  }
  __syncthreads();

  // wave wv handles rows r0 + wv*16 .. +15, both halves (A then C)
  F8 aop[2];
  #pragma unroll
  for (int ks = 0; ks < 2; ++ks)
    aop[ks].v = *(const bf16x8*)&s_ob[wv * 16 + lo][ks * 32 + g * 8];

  #pragma unroll
  for (int half = 0; half < 2; ++half) {
    #pragma unroll
    for (int nf = 0; nf < 4; ++nf) {
      f32x4 ac = {0.f, 0.f, 0.f, 0.f};
      #pragma unroll
      for (int ks = 0; ks < 2; ++ks) {
        F8 bop; bop.v = *(const bf16x8*)&wtg[(nf * 16 + lo) * 256 + half * 64 + ks * 32 + g * 8];
        MFMA(ac, aop[ks].v, bop.v);
      }
      const int h = nf * 16 + lo;
      if (half == 0) {
        float bb = b1[h];
        #pragma unroll
        for (int r = 0; r < 4; ++r)
          Ag[((size_t)b * Nn + r0 + wv * 16 + g * 4 + r) * 64 + h] = ac[r] + bb;
      } else {
        #pragma unroll
        for (int r = 0; r < 4; ++r) {
          __bf16 cb = (__bf16)ac[r];
          Cgb[((size_t)b * Nn + r0 + wv * 16 + g * 4 + r) * 64 + h] = *(unsigned short*)&cb;
        }
      }
    }
  }
}

// ---------------------------------------------------------------------------
// Pair kernel: one block = (batch, 16x32 pair tile), 256 thr (4 waves).
// XCD-aware decode: XCD x serves only batches {2x, 2x+1}.
// launch_bounds(256,2): min-waves=3 FORCED SCRATCH SPILL in r5-r9 (VGPR 84 +
// 11-44 MB scratch writes); cap 256 lets the ~180-reg hoisted set stay live.
// ---------------------------------------------------------------------------
__global__ __launch_bounds__(256, 2) void pair_kernel(
    const unsigned short* __restrict__ obg,
    const float* __restrict__ Ag,
    const unsigned short* __restrict__ Cgb,
    const float* __restrict__ W2,
    const float* __restrict__ b2,
    const unsigned short* __restrict__ wtg,
    float* __restrict__ Q,
    float* __restrict__ cand)
{
  __shared__ __align__(16) unsigned short s_wt[64][136]; // pairwise W^T bf16 [h][k-128]
  __shared__ __align__(16) unsigned short s_oi[16][72];
  __shared__ __align__(16) unsigned short s_oj[32][72];
  __shared__ float s_A [16][68];  // A[i][h] (+b1)
  __shared__ float s_q [16][36];
  __shared__ float s_w2[64];
  __shared__ float s_red[4][4];

  const int t  = threadIdx.x;
  const int l  = t & 63, wv = t >> 6;
  const int lo = l & 15, g = l >> 4;

  const int blk    = blockIdx.x;
  const int within = blk >> 3;                    // 0..143
  const int batch  = (blk & 7) * 2 + within / 72; // XCD (blk%8) -> batches 2x,2x+1
  int tl           = within % 72;
  int a = 0;
  while (tl >= 8 - (a >> 1)) { tl -= 8 - (a >> 1); ++a; }
  const int c   = (a >> 1) + tl;
  const int ti0 = a * 16, tj0 = c * 32;

  // ---- stage: W pairwise half (16 KB), O tiles (bf16 copy), A rows ----
  {
    const int h = t >> 2, kq = (t & 3) * 32;
    #pragma unroll
    for (int q = 0; q < 4; ++q) {
      *(bf16x8*)&s_wt[h][kq + q * 8] =
          *(const bf16x8*)&wtg[h * 256 + 128 + kq + q * 8];
    }
  }
  {
    int r = t >> 4, c4 = (t & 15) * 4;
    *(short4v*)&s_oi[r][c4] =
        *(const short4v*)&obg[((size_t)batch * Nn + ti0 + r) * 64 + c4];
    *(f32x4*)&s_A[r][c4] =
        *(const f32x4*)&Ag[((size_t)batch * Nn + ti0 + r) * 64 + c4];
    #pragma unroll
    for (int p = 0; p < 2; ++p) {
      int v = t + p * 256;
      int rj = v >> 4, cj = (v & 15) * 4;
      *(short4v*)&s_oj[rj][cj] =
          *(const short4v*)&obg[((size_t)batch * Nn + tj0 + rj) * 64 + cj];
    }
    if (t < 64) s_w2[t] = W2[t];
  }
  __syncthreads();

  // ---- hoists: W frags (from LDS: remat-safe), oj bf16, C-init bf16 ----
  F8 bfr[4][4];   // [ks][nf]
  #pragma unroll
  for (int ks = 0; ks < 4; ++ks)
    #pragma unroll
    for (int nf = 0; nf < 4; ++nf)
      bfr[ks][nf].v = *(const bf16x8*)&s_wt[nf * 16 + lo][ks * 32 + g * 8];

  F8 ojb[2][2];
  #pragma unroll
  for (int jh = 0; jh < 2; ++jh) {
    ojb[jh][0].v = *(const bf16x8*)&s_oj[jh * 16 + lo][g * 8];
    ojb[jh][1].v = *(const bf16x8*)&s_oj[jh * 16 + lo][32 + g * 8];
  }
  F4 cinb[2][4];  // C[j= tj0+jh*16+lo][nf*16+g*4 ..+3] bf16 (global, L2-hot)
  #pragma unroll
  for (int jh = 0; jh < 2; ++jh)
    #pragma unroll
    for (int nf = 0; nf < 4; ++nf)
      cinb[jh][nf].v = *(const short4v*)
          &Cgb[((size_t)batch * Nn + tj0 + jh * 16 + lo) * 64 + nf * 16 + g * 4];

  // ---- main loop: wave owns i-rows wv*4 .. wv*4+3 ----
  for (int ii = 0; ii < 4; ++ii) {
    const int iL = wv * 4 + ii;

    float oiv[16];
    {
      F8 u0, u1;
      u0.v = *(const bf16x8*)&s_oi[iL][g * 8];
      u1.v = *(const bf16x8*)&s_oi[iL][32 + g * 8];
      #pragma unroll
      for (int e = 0; e < 8; ++e) {
        oiv[e]     = (float)u0.h[e];
        oiv[8 + e] = (float)u1.h[e];
      }
    }
    f32x4 as4[4];
    #pragma unroll
    for (int nf = 0; nf < 4; ++nf)
      as4[nf] = *(const f32x4*)&s_A[iL][nf * 16 + g * 4];

    #pragma unroll
    for (int jh = 0; jh < 2; ++jh) {
      F8 fb0, fb1, fb2, fb3;
      #pragma unroll
      for (int e = 0; e < 8; ++e) {
        float p0 = (float)ojb[jh][0].h[e];
        float p1 = (float)ojb[jh][1].h[e];
        fb0.h[e] = (__bf16)fabsf(oiv[e]     - p0);
        fb1.h[e] = (__bf16)fabsf(oiv[8 + e] - p1);
        fb2.h[e] = (__bf16)(oiv[e]     * p0);
        fb3.h[e] = (__bf16)(oiv[8 + e] * p1);
      }

      f32x4 acc[4] = { as4[0], as4[1], as4[2], as4[3] };
      #pragma unroll
      for (int nf = 0; nf < 4; ++nf) {
        MFMA(acc[nf], bfr[0][nf].v, fb0.v);
        MFMA(acc[nf], bfr[1][nf].v, fb1.v);
        MFMA(acc[nf], bfr[2][nf].v, fb2.v);
        MFMA(acc[nf], bfr[3][nf].v, fb3.v);
      }

      // epilogue: + C (bf16->f32), relu, W2 dot, reduce over g
      float part = 0.f;
      #pragma unroll
      for (int nf = 0; nf < 4; ++nf) {
        #pragma unroll
        for (int r = 0; r < 4; ++r) {
          float z = acc[nf][r] + (float)cinb[jh][nf].h[r];
          part = fmaf(fmaxf(z, 0.f), s_w2[nf * 16 + g * 4 + r], part);
        }
      }
      part += __shfl_xor(part, 16);
      part += __shfl_xor(part, 32);
      if (g == 0) s_q[iL][jh * 16 + lo] = part;
    }
  }
  __syncthreads();

  // ---- final: Q store + block top-2 candidates ----
  {
    const float b2v = b2[0];
    const int e0 = t * 2;
    const int row = e0 >> 5, col0 = e0 & 31;
    const int i = ti0 + row;
    float v1 = -INFINITY, v2 = -INFINITY;
    int   i1 = 0x7fffffff, i2 = 0x7fffffff;
    const int mbase = i * (Nn - 1) - (i * (i - 1)) / 2 - i - 1;
    #pragma unroll
    for (int e = 0; e < 2; ++e) {
      const int col = col0 + e;
      const int j = tj0 + col;
      const float qv = s_q[row][col] + b2v;
      if (j > i) {
        const int m = mbase + j;
        Q[(size_t)batch * Mm + m] = qv;
        top2_update(qv, m, v1, i1, v2, i2);
      }
    }
    #pragma unroll
    for (int s = 1; s < 64; s <<= 1) {
      float u1 = __shfl_xor(v1, s); int j1 = __shfl_xor(i1, s);
      float u2 = __shfl_xor(v2, s); int j2 = __shfl_xor(i2, s);
      top2_update(u1, j1, v1, i1, v2, i2);
      top2_update(u2, j2, v1, i1, v2, i2);
    }
    if (l == 0) {
      s_red[wv][0] = v1; s_red[wv][1] = __int_as_float(i1);
      s_red[wv][2] = v2; s_red[wv][3] = __int_as_float(i2);
    }
    __syncthreads();
    if (t == 0) {
      float a1 = s_red[0][0]; int x1 = __float_as_int(s_red[0][1]);
      float a2 = s_red[0][2]; int x2 = __float_as_int(s_red[0][3]);
      #pragma unroll
      for (int e = 1; e < 4; ++e) {
        top2_update(s_red[e][0], __float_as_int(s_red[e][1]), a1, x1, a2, x2);
        top2_update(s_red[e][2], __float_as_int(s_red[e][3]), a1, x1, a2, x2);
      }
      // cand indexed by (batch, tile) for rankmask
      float* cp = cand + ((size_t)batch * 72 + within % 72) * 4;
      cp[0] = a1; cp[1] = __int_as_float(x1);
      cp[2] = a2; cp[3] = __int_as_float(x2);
    }
  }
}

// ---------------------------------------------------------------------------
// Rank+mask kernel: grid (B x 8). Each block redundantly merges the 144
// candidates -> top-8 (by bf16 Q), recomputes those 8 exactly in fp32
// (wave-per-candidate, h-per-lane: coalesced W1 reads + wave reduce),
// picks exact top-2 (jax tie rule: lower index), writes its mask slice.
// ---------------------------------------------------------------------------
__global__ __launch_bounds__(256) void rankmask_kernel(
    const float* __restrict__ O, const float* __restrict__ W1,
    const float* __restrict__ b1, const float* __restrict__ W2,
    const float* __restrict__ cand, float* __restrict__ mask)
{
  const int b   = blockIdx.x >> 3;
  const int cch = blockIdx.x & 7;
  const int t   = threadIdx.x;
  const int wv  = t >> 6, h = t & 63;
  __shared__ float s_cv[144];
  __shared__ int   s_ci[144];
  __shared__ int   s_m[8];
  __shared__ int   s_ij[8][2];
  __shared__ float s_or[8][2][64];
  __shared__ float s_qe[8];
  __shared__ int   s_k0, s_k1;

  if (t < 144) {
    const float* cp = cand + (size_t)(b * 72 + (t >> 1)) * 4;
    s_cv[t] = cp[(t & 1) * 2];
    s_ci[t] = __float_as_int(cp[(t & 1) * 2 + 1]);
  }
  __syncthreads();
  if (t < 144) {
    float v = s_cv[t]; int m = s_ci[t];
    int rank = 0;
    for (int e = 0; e < 144; ++e) {
      float u = s_cv[e]; int n = s_ci[e];
      rank += (u > v || (u == v && n < m)) ? 1 : 0;
    }
    if (rank < 8) s_m[rank] = m;
  }
  __syncthreads();
  if (t < 16) {
    int m = s_m[t >> 1];
    int i = 0, rem = m;
    while (rem >= Nn - 1 - i) { rem -= Nn - 1 - i; ++i; }
    int j = i + 1 + rem;
    s_ij[t >> 1][t & 1] = (t & 1) ? j : i;
  }
  __syncthreads();
  {
    int cc = t >> 5, rr = (t >> 4) & 1, c4 = (t & 15) * 4;
    int row = s_ij[cc][rr];
    *(float4*)&s_or[cc][rr][c4] = *(const float4*)&O[((size_t)b * Nn + row) * 64 + c4];
  }
  __syncthreads();
  // exact fp32 recompute: wave wv handles candidate c = p*4 + wv, lane = h
  #pragma unroll
  for (int p = 0; p < 2; ++p) {
    const int cc = p * 4 + wv;
    float z = b1[h];
    #pragma unroll 8
    for (int d = 0; d < 64; ++d) {
      float oi = s_or[cc][0][d], oj = s_or[cc][1][d];
      float f3 = fabsf(oi - oj), f4 = oi * oj;
      z += oi * W1[d * 64 + h] + oj * W1[(64 + d) * 64 + h]
         + f3 * W1[(128 + d) * 64 + h] + f4 * W1[(192 + d) * 64 + h];
    }
    float part = fmaxf(z, 0.f) * W2[h];
    #pragma unroll
    for (int s = 1; s < 64; s <<= 1) part += __shfl_xor(part, s);
    if (h == 0) s_qe[cc] = part;
  }
  __syncthreads();
  if (t == 0) {
    float v1 = -INFINITY, v2 = -INFINITY;
    int   i1 = 0x7fffffff, i2 = 0x7fffffff;
    for (int e = 0; e < 8; ++e)
      top2_update(s_qe[e], s_m[e], v1, i1, v2, i2);
    s_k0 = i1; s_k1 = i2;
  }
  __syncthreads();

  const int k0 = s_k0, k1 = s_k1;
  float* mb = mask + (size_t)b * Mm;
  const int m0 = cch * CHUNK;
  for (int m = m0 + t; m < m0 + CHUNK; m += 256)
    mb[m] = (m == k0 || m == k1) ? 1.0f : 0.0f;
}

extern "C" void kernel_launch(void* const* d_in, const int* in_sizes, int n_in,
                              void* d_out, int out_size, void* d_ws, size_t ws_size,
                              hipStream_t stream) {
  const float* O  = (const float*)d_in[0];
  const float* W1 = (const float*)d_in[1];
  const float* b1 = (const float*)d_in[2];
  const float* W2 = (const float*)d_in[3];
  const float* b2 = (const float*)d_in[4];

  float* Q    = (float*)d_out;
  float* mask = Q + (size_t)Bn * Mm;

  char* ws = (char*)d_ws;
  unsigned short* wtg = (unsigned short*)ws;                  // 32768 B
  unsigned short* obg = (unsigned short*)(ws + 32768);        // 524288 B
  float*          Ag  = (float*)(ws + 32768 + 524288);        // 1048576 B
  unsigned short* Cgb = (unsigned short*)(ws + 32768 + 524288 + 1048576);  // 524288 B
  float*          cand = (float*)(ws + 32768 + 524288 + 1048576 + 524288); // 18432 B

  prep_w1t<<<dim3(64), dim3(256), 0, stream>>>(W1, wtg);
  prep_ac<<<dim3(Bn * 4), dim3(256), 0, stream>>>(O, b1, wtg, obg, Ag, Cgb);
  pair_kernel<<<dim3(Bn * 72), dim3(256), 0, stream>>>(obg, Ag, Cgb, W2, b2, wtg, Q, cand);
  rankmask_kernel<<<dim3(Bn * 8), dim3(256), 0, stream>>>(O, W1, b1, W2, cand, mask);
}